// Round 8
// baseline (533.120 us; speedup 1.0000x reference)
//
#include <hip/hip_runtime.h>

// C51 distributional Q target: operand-swapped MFMA (D = W * X^T), each lane
// owns 4 consecutive FEATURES of one batch ROW; LN/SiLU/softmax in registers.
// R8: 64 rows/block, 8 waves (feature-eighth each), rt=4 row-tiles/wave ->
// each a-frag feeds 4 MFMAs (2x R5), weight loads per CU halved, per-row
// barrier/LN overhead halved. 70.3KB LDS -> 2 blocks/CU = 16 waves/CU (same
// as R5). a-ring depth-3; b single-buffered; scalars loaded post-GEMM4.

#define THREADS 512
#define PREP_THREADS 256

typedef __attribute__((ext_vector_type(8))) short short8v;
typedef __attribute__((ext_vector_type(4))) float f32x4;

__device__ __forceinline__ unsigned short f2bf(float f) {
  union { float f; unsigned u; } v; v.f = f;
  unsigned u = v.u;
  u += 0x7fffu + ((u >> 16) & 1u);   // RNE
  return (unsigned short)(u >> 16);
}
// HW packed fp32->bf16 (RNE), 1 VALU inst for 2 values
__device__ __forceinline__ unsigned pack2bf(float a, float b) {
  unsigned r;
  asm("v_cvt_pk_bf16_f32 %0, %1, %2" : "=v"(r) : "v"(a), "v"(b));
  return r;
}

// ---------------- prep: weights fp32 [K][N] -> bf16 [N][K] in ws -------------
// W1T @0 (512x160), W2T @81920 (256x512), W3T @212992 (128x256),
// W4T @245760 (256x128, rows n>=251 zero-padded)
__global__ void prep_kernel(const float* __restrict__ W1, const float* __restrict__ W2,
                            const float* __restrict__ W3, const float* __restrict__ W4,
                            unsigned short* __restrict__ ws) {
  int i = blockIdx.x * PREP_THREADS + threadIdx.x;
  if (i < 81920) {
    int n = i / 160, k = i - n * 160;
    ws[i] = f2bf(W1[k * 512 + n]);
  } else if (i < 212992) {
    int j = i - 81920; int n = j >> 9, k = j & 511;
    ws[i] = f2bf(W2[k * 256 + n]);
  } else if (i < 245760) {
    int j = i - 212992; int n = j >> 8, k = j & 255;
    ws[i] = f2bf(W3[k * 128 + n]);
  } else if (i < 278528) {
    int j = i - 245760; int n = j >> 7, k = j & 127;
    ws[i] = (n < 251) ? f2bf(W4[k * 251 + n]) : (unsigned short)0;
  }
}

// LDS layout (bytes). ONE time-multiplexed 64KB region R @0:
//   X bf16 [64][160] swz (20KB) -> H1 [64][512] swz (64KB) ->
//   H2 [64][256] swz (32KB) -> H3 [64][128] swz (16KB) ->
//   proj f32 [64][251] (62.8KB)
// Every overwrite is fenced by the LN/softmax internal __syncthreads.
#define OFF_R   0
#define OFF_ZS  65536
#define OFF_B4  66560
#define OFF_RED 67584
#define LDS_TOTAL 71936   // 67584 + 64*17*4

// GEMM: acc[ft][rt] += WT[fbase+ft*16+..][k] * H[rt*16+..][k]
// MFMA 16x16x32 bf16, A = weight rows (m=feature), B = act rows (n=batch row).
// D: lane&15 = batch row in tile, (lane>>4)*4+reg = feature in tile.
// a-frags: ring buffer, prefetch PF=DEPTH-1 items ahead (L2 ~250cy), each
// a-frag feeds 4 MFMAs. b-frags: single-buffered per ks (compiler pipelines
// LDS reads well). All indices compile-time after full unroll.
template<int KD, int NFT, int FPG, int DEPTH>
__device__ __forceinline__ void gemm_w(const unsigned short* __restrict__ WT,
                                       const unsigned char* __restrict__ Hb,
                                       int fbase, f32x4 (&acc)[NFT][4]) {
  const int lane = threadIdx.x & 63;
  const int lm = lane & 15, kg = lane >> 4;
  constexpr int KS  = KD / 32;
  constexpr int G   = NFT / FPG;
  constexpr int NIT = KS * G;
  constexpr int PF  = DEPTH - 1;   // a-frag item prefetch distance

  const int woff0 = (fbase + lm) * KD + kg * 8;
  // b-frag LDS byte offsets: per-rt, per-ks-parity (swizzle XOR covers bits
  // 4..6; bit6 of ks*64 folds into parity, higher bits advance by 128B/pair).
  int boff[4][2];
#pragma unroll
  for (int rt = 0; rt < 4; ++rt) {
    const int r = rt * 16 + lm;
    const int swz = (r & 7) << 4;
    const int base = r * (KD * 2) + kg * 16;
    boff[rt][0] = base ^ swz;
    boff[rt][1] = (base + 64) ^ swz;
  }

  short8v abuf[DEPTH][FPG];
  short8v bbuf[4];

  // prologue: a for items 0..PF-1
#pragma unroll
  for (int p = 0; p < PF && p < NIT; ++p) {
    const int g = p % G, ks = p / G;
#pragma unroll
    for (int f = 0; f < FPG; ++f)
      abuf[p % DEPTH][f] =
          *(const short8v*)(WT + woff0 + (g * FPG + f) * (16 * KD) + ks * 32);
  }

#pragma unroll
  for (int it = 0; it < NIT; ++it) {
    const int ks = it / G, g = it % G;
    // b load for this ks (first item of the ks)
    if (g == 0) {
      const int koff = (ks >> 1) * 128;
#pragma unroll
      for (int rt = 0; rt < 4; ++rt)
        bbuf[rt] = *(const short8v*)(Hb + boff[rt][ks & 1] + koff);
    }
    // a prefetch: item it+PF
    if (it + PF < NIT) {
      const int nit = it + PF;
      const int ng = nit % G, nks = nit / G;
#pragma unroll
      for (int f = 0; f < FPG; ++f)
        abuf[nit % DEPTH][f] =
            *(const short8v*)(WT + woff0 + (ng * FPG + f) * (16 * KD) + nks * 32);
    }
    // compute item it: FPG a-frags x 4 row-tiles
#pragma unroll
    for (int f = 0; f < FPG; ++f) {
      const int ft = g * FPG + f;
#pragma unroll
      for (int rt = 0; rt < 4; ++rt)
        acc[ft][rt] = __builtin_amdgcn_mfma_f32_16x16x32_bf16(
            abuf[it % DEPTH][f], bbuf[rt], acc[ft][rt], 0, 0, 0);
    }
  }
}

// bias + LayerNorm + SiLU entirely in registers, then one packed b64 store
// per (ft, rt) into swizzled LDS [64][ND] bf16. 8 waves reduce via redL
// (stride 17). Internal barrier doubles as the region-reuse fence.
template<int ND, int NFT>
__device__ __forceinline__ void ln_silu_store(
    f32x4 (&acc)[NFT][4],
    const float* __restrict__ bias, const float* __restrict__ g,
    const float* __restrict__ be, unsigned char* __restrict__ Hb,
    float* __restrict__ redL, int fbase, int fq)
{
  const int lane = threadIdx.x & 63;
  const int lm = lane & 15, kg = lane >> 4;
  float s[4] = {0.f, 0.f, 0.f, 0.f}, q[4] = {0.f, 0.f, 0.f, 0.f};
#pragma unroll
  for (int ft = 0; ft < NFT; ++ft) {
    const int f0 = fbase + ft * 16 + kg * 4;
    const f32x4 bb = *(const f32x4*)(bias + f0);
#pragma unroll
    for (int rt = 0; rt < 4; ++rt)
#pragma unroll
      for (int rg = 0; rg < 4; ++rg) {
        float x = acc[ft][rt][rg] + bb[rg];
        acc[ft][rt][rg] = x;
        s[rt] += x; q[rt] += x * x;
      }
  }
#pragma unroll
  for (int rt = 0; rt < 4; ++rt) {
    s[rt] += __shfl_xor(s[rt], 16); s[rt] += __shfl_xor(s[rt], 32);
    q[rt] += __shfl_xor(q[rt], 16); q[rt] += __shfl_xor(q[rt], 32);
  }
  if (lane < 16) {
#pragma unroll
    for (int rt = 0; rt < 4; ++rt) {
      redL[(rt * 16 + lm) * 17 + fq * 2    ] = s[rt];
      redL[(rt * 16 + lm) * 17 + fq * 2 + 1] = q[rt];
    }
  }
  __syncthreads();
  float mean[4], rstd[4];
#pragma unroll
  for (int rt = 0; rt < 4; ++rt) {
    const int row = rt * 16 + lm;
    float S = 0.f, Q = 0.f;
#pragma unroll
    for (int w = 0; w < 8; ++w) {
      S += redL[row * 17 + w * 2];
      Q += redL[row * 17 + w * 2 + 1];
    }
    float m = S * (1.0f / ND);
    float v = Q * (1.0f / ND) - m * m;
    mean[rt] = m; rstd[rt] = rsqrtf(v + 1e-5f);
  }
#pragma unroll
  for (int ft = 0; ft < NFT; ++ft) {
    const int f0 = fbase + ft * 16 + kg * 4;
    const f32x4 g4 = *(const f32x4*)(g + f0);
    const f32x4 e4 = *(const f32x4*)(be + f0);
#pragma unroll
    for (int rt = 0; rt < 4; ++rt) {
      const int row = rt * 16 + lm;
      float h[4];
#pragma unroll
      for (int rg = 0; rg < 4; ++rg) {
        float y = (acc[ft][rt][rg] - mean[rt]) * rstd[rt] * g4[rg] + e4[rg];
        h[rg] = y * (1.0f / (1.0f + __expf(-y)));
      }
      uint2 w; w.x = pack2bf(h[0], h[1]); w.y = pack2bf(h[2], h[3]);
      int byte = row * (ND * 2) + f0 * 2;
      byte ^= ((row & 7) << 4);
      *(uint2*)(Hb + byte) = w;
    }
  }
}

__global__ __launch_bounds__(THREADS, 4) void fused_kernel(
    const float* __restrict__ obs, const float* __restrict__ actions,
    const float* __restrict__ rewards, const float* __restrict__ bootstrap,
    const float* __restrict__ discount, const float* __restrict__ q_support,
    const float* __restrict__ b1, const float* __restrict__ g1, const float* __restrict__ be1,
    const float* __restrict__ b2, const float* __restrict__ g2, const float* __restrict__ be2,
    const float* __restrict__ b3, const float* __restrict__ g3, const float* __restrict__ be3,
    const float* __restrict__ b4,
    const unsigned short* __restrict__ ws,
    float* __restrict__ out)
{
  __shared__ __align__(16) unsigned char smem[LDS_TOTAL];
  const int tid  = threadIdx.x;
  const int fq   = tid >> 6;          // wave = feature-eighth, 0..7
  const int lane = tid & 63;
  const int lm   = lane & 15;
  const int kg   = lane >> 4;
  const int row0 = blockIdx.x * 64;

  const unsigned short* W1T = ws;
  const unsigned short* W2T = ws + 81920;
  const unsigned short* W3T = ws + 212992;
  const unsigned short* W4T = ws + 245760;

  float* zsL  = (float*)(smem + OFF_ZS);
  float* b4L  = (float*)(smem + OFF_B4);
  float* redL = (float*)(smem + OFF_RED);

  // stage q_support / b4 (padded to 256, avoids OOB vector loads)
  if (tid < 256) {
    zsL[tid] = (tid < 251) ? q_support[tid] : 0.f;
    b4L[tid] = (tid < 251) ? b4[tid] : 0.f;
  }

  // stage X = concat(obs, actions) bf16 [64][160], swizzled (2560 uint2)
  {
    unsigned char* Xb = smem + OFF_R;
#pragma unroll
    for (int it = 0; it < 5; ++it) {
      const int qq = it * THREADS + tid;     // 0..2559, 40 float4 per row
      const int r  = qq / 40;
      const int c4 = (qq - r * 40) * 4;
      float4 v;
      if (c4 < 128) v = *(const float4*)(obs + (size_t)(row0 + r) * 128 + c4);
      else          v = *(const float4*)(actions + (size_t)(row0 + r) * 32 + (c4 - 128));
      uint2 w; w.x = pack2bf(v.x, v.y); w.y = pack2bf(v.z, v.w);
      int byte = r * 320 + c4 * 2;
      byte ^= ((r & 7) << 4);
      *(uint2*)(Xb + byte) = w;
    }
  }
  __syncthreads();

  // ---- layer 1: 512 feats, K=160; 64 feats/wave ----
  f32x4 acc1[4][4];
#pragma unroll
  for (int i = 0; i < 4; ++i)
#pragma unroll
    for (int j = 0; j < 4; ++j) acc1[i][j] = f32x4{0.f, 0.f, 0.f, 0.f};
  gemm_w<160, 4, 2, 3>(W1T, smem + OFF_R, fq * 64, acc1);
  ln_silu_store<512, 4>(acc1, b1, g1, be1, smem + OFF_R, redL, fq * 64, fq);
  __syncthreads();

  // ---- layer 2: 256 feats, K=512; 32 feats/wave ----
  f32x4 acc2[2][4];
#pragma unroll
  for (int i = 0; i < 2; ++i)
#pragma unroll
    for (int j = 0; j < 4; ++j) acc2[i][j] = f32x4{0.f, 0.f, 0.f, 0.f};
  gemm_w<512, 2, 2, 3>(W2T, smem + OFF_R, fq * 32, acc2);
  ln_silu_store<256, 2>(acc2, b2, g2, be2, smem + OFF_R, redL, fq * 32, fq);
  __syncthreads();

  // ---- layer 3: 128 feats, K=256; 16 feats/wave ----
  f32x4 acc3[1][4];
#pragma unroll
  for (int j = 0; j < 4; ++j) acc3[0][j] = f32x4{0.f, 0.f, 0.f, 0.f};
  gemm_w<256, 1, 1, 3>(W3T, smem + OFF_R, fq * 16, acc3);
  ln_silu_store<128, 1>(acc3, b3, g3, be3, smem + OFF_R, redL, fq * 16, fq);
  __syncthreads();

  // ---- layer 4: logits, 256pad feats, K=128; 32 feats/wave ----
  f32x4 acc4[2][4];
#pragma unroll
  for (int i = 0; i < 2; ++i)
#pragma unroll
    for (int j = 0; j < 4; ++j) acc4[i][j] = f32x4{0.f, 0.f, 0.f, 0.f};
  gemm_w<128, 2, 2, 3>(W4T, smem + OFF_R, fq * 32, acc4);

  // per-row scalars (loaded now, overlapping softmax; not live through GEMMs)
  float rw[4], bt[4], dc[4];
#pragma unroll
  for (int rt = 0; rt < 4; ++rt) {
    const int r = row0 + rt * 16 + lm;
    rw[rt] = rewards[r]; bt[rt] = bootstrap[r]; dc[rt] = discount[r];
  }

  float lv[2][4][4];
#pragma unroll
  for (int ft = 0; ft < 2; ++ft) {
    const int f0 = fq * 32 + ft * 16 + kg * 4;
    const f32x4 bb = *(const f32x4*)(b4L + f0);
#pragma unroll
    for (int rt = 0; rt < 4; ++rt)
#pragma unroll
      for (int rg = 0; rg < 4; ++rg) {
        const int f = f0 + rg;
        lv[ft][rt][rg] = (f < 251) ? (acc4[ft][rt][rg] + bb[rg]) : -1e30f;
      }
  }

  // ---- softmax over 251 features per row (stride-9 padded reduction) ----
#pragma unroll
  for (int rt = 0; rt < 4; ++rt) {
    float m = lv[0][rt][0];
#pragma unroll
    for (int ft = 0; ft < 2; ++ft)
#pragma unroll
      for (int rg = 0; rg < 4; ++rg) m = fmaxf(m, lv[ft][rt][rg]);
    m = fmaxf(m, __shfl_xor(m, 16));
    m = fmaxf(m, __shfl_xor(m, 32));
    if (lane < 16) redL[(rt * 16 + lm) * 9 + fq] = m;
  }
  __syncthreads();   // all waves past GEMM4's H3 reads; redL max visible

  // zero proj buffer (region R; overwrites H3 — dead now)
  float* projL = (float*)(smem + OFF_R);
  for (int i = tid; i < 64 * 251; i += THREADS) projL[i] = 0.f;

  float gm[4];
#pragma unroll
  for (int rt = 0; rt < 4; ++rt) {
    const int row = rt * 16 + lm;
    float m = redL[row * 9];
#pragma unroll
    for (int w = 1; w < 8; ++w) m = fmaxf(m, redL[row * 9 + w]);
    gm[rt] = m;
  }
  __syncthreads();   // redL reuse + proj zeros visible
#pragma unroll
  for (int rt = 0; rt < 4; ++rt) {
    float E = 0.f;
#pragma unroll
    for (int ft = 0; ft < 2; ++ft)
#pragma unroll
      for (int rg = 0; rg < 4; ++rg) {
        float e = __expf(lv[ft][rt][rg] - gm[rt]);
        lv[ft][rt][rg] = e;
        E += e;
      }
    E += __shfl_xor(E, 16); E += __shfl_xor(E, 32);
    if (lane < 16) redL[(rt * 16 + lm) * 9 + fq] = E;
  }
  __syncthreads();
  float inv[4];
#pragma unroll
  for (int rt = 0; rt < 4; ++rt) {
    const int row = rt * 16 + lm;
    float E = 0.f;
#pragma unroll
    for (int w = 0; w < 8; ++w) E += redL[row * 9 + w];
    inv[rt] = 1.0f / E;
  }

  // ---- C51 projection scatter ----
  // b = (t+10) * (1/DZ): <=1ulp off the correctly-rounded divide; the
  // two-point interpolation is continuous in b, so output error is O(1e-7).
  constexpr float DZF = 20.0f / 250.0f;
  constexpr float INVDZ = 1.0f / DZF;
#pragma unroll
  for (int ft = 0; ft < 2; ++ft) {
    const int f0 = fq * 32 + ft * 16 + kg * 4;
    const f32x4 z4 = *(const f32x4*)(zsL + f0);
#pragma unroll
    for (int rt = 0; rt < 4; ++rt) {
      const int base = (rt * 16 + lm) * 251;
      const float bd = __fmul_rn(bt[rt], dc[rt]);
#pragma unroll
      for (int rg = 0; rg < 4; ++rg) {
        const int f = f0 + rg;
        if (f < 251) {
          const float p = lv[ft][rt][rg] * inv[rt];
          float t = __fadd_rn(rw[rt], __fmul_rn(bd, z4[rg]));
          t = fminf(fmaxf(t, -10.0f), 10.0f);
          const float bfr = __fmul_rn(__fsub_rn(t, -10.0f), INVDZ);
          const float fl = floorf(bfr), fu = ceilf(bfr);
          int l = (int)fl, u = (int)fu;
          if (fl == fu) { if (l > 0) --l; else ++u; }
          atomicAdd(projL + base + l, p * ((float)u - bfr));
          atomicAdd(projL + base + u, p * (bfr - (float)l));
        }
      }
    }
  }
  __syncthreads();

  // ---- write out: block slice contiguous (64*251 floats = 4016 float4) ----
  const float4* ps = (const float4*)projL;
  float4* po = (float4*)(out + (size_t)row0 * 251);
  for (int i = tid; i < 4016; i += THREADS) po[i] = ps[i];
}

extern "C" void kernel_launch(void* const* d_in, const int* in_sizes, int n_in,
                              void* d_out, int out_size, void* d_ws, size_t ws_size,
                              hipStream_t stream) {
  const float* obs  = (const float*)d_in[0];
  const float* act  = (const float*)d_in[1];
  const float* rew  = (const float*)d_in[2];
  const float* boot = (const float*)d_in[3];
  const float* disc = (const float*)d_in[4];
  const float* zs   = (const float*)d_in[5];
  const float* W1   = (const float*)d_in[6];
  const float* b1   = (const float*)d_in[7];
  const float* g1   = (const float*)d_in[8];
  const float* be1  = (const float*)d_in[9];
  const float* W2   = (const float*)d_in[10];
  const float* b2   = (const float*)d_in[11];
  const float* g2   = (const float*)d_in[12];
  const float* be2  = (const float*)d_in[13];
  const float* W3   = (const float*)d_in[14];
  const float* b3   = (const float*)d_in[15];
  const float* g3   = (const float*)d_in[16];
  const float* be3  = (const float*)d_in[17];
  const float* W4   = (const float*)d_in[18];
  const float* b4   = (const float*)d_in[19];
  unsigned short* wsp = (unsigned short*)d_ws;

  const int Bn = in_sizes[2];          // batch = 131072
  prep_kernel<<<(278528 + PREP_THREADS - 1) / PREP_THREADS, PREP_THREADS, 0, stream>>>(
      W1, W2, W3, W4, wsp);
  fused_kernel<<<Bn / 64, THREADS, 0, stream>>>(obs, act, rew, boot, disc, zs,
      b1, g1, be1, b2, g2, be2, b3, g3, be3, b4, wsp, (float*)d_out);
}